// Round 4
// baseline (116.939 us; speedup 1.0000x reference)
//
#include <hip/hip_runtime.h>
#include <hip/hip_bf16.h>

typedef unsigned short u16;
typedef __bf16 bf16x8 __attribute__((ext_vector_type(8)));
typedef float f32x4 __attribute__((ext_vector_type(4)));

// ---- manual fp32 -> bf16 (round-to-nearest-even) ----
__device__ __forceinline__ u16 f2bf(float f) {
    unsigned u = __float_as_uint(f);
    u = u + 0x7fffu + ((u >> 16) & 1u);   // RNE
    return (u16)(u >> 16);
}
__device__ __forceinline__ float bflo(unsigned u) { return __uint_as_float(u << 16); }
__device__ __forceinline__ float bfhi(unsigned u) { return __uint_as_float(u & 0xffff0000u); }

// =====================================================================================
// K0: fp32 -> bf16 convert (W only, 64Ki elements — tiny)
// =====================================================================================
__global__ __launch_bounds__(256) void k_convert(const float* __restrict__ src,
                                                 u16* __restrict__ dst, int n4) {
    int i = blockIdx.x * blockDim.x + threadIdx.x;
    if (i >= n4) return;
    float4 v = reinterpret_cast<const float4*>(src)[i];
    ushort4 o;
    o.x = f2bf(v.x); o.y = f2bf(v.y); o.z = f2bf(v.z); o.w = f2bf(v.w);
    reinterpret_cast<ushort4*>(dst)[i] = o;
}

// =====================================================================================
// K1: Y = emb @ W^T  (linearity: transform BEFORE gather/mean)
// emb fp32 read, converted to bf16 in-register; Y written bf16.
// block = 256 thr (4 waves); tile 64 rows x 256 cols; wave tile 64x64.
// =====================================================================================
__global__ __launch_bounds__(256) void k_emb_gemm(
        const float* __restrict__ emb,   // [n][256] fp32
        const u16* __restrict__ wbf,     // [256][256] bf16 (row = out_dim, col = k)
        u16* __restrict__ Y,             // [n][256] bf16
        int n_nodes) {
    int tid  = threadIdx.x;
    int lane = tid & 63;
    int w    = tid >> 6;
    int r0   = blockIdx.x * 64;
    int c0   = w * 64;
    int l15  = lane & 15;
    int lg   = lane >> 4;                // k-subblock of 8

    const bf16x8*  B8 = reinterpret_cast<const bf16x8*>(wbf);
    const float4*  A4 = reinterpret_cast<const float4*>(emb);

    f32x4 acc[4][4];
    #pragma unroll
    for (int mt = 0; mt < 4; ++mt)
        #pragma unroll
        for (int nt = 0; nt < 4; ++nt)
            acc[mt][nt] = (f32x4){0.f, 0.f, 0.f, 0.f};

    #pragma unroll
    for (int kt = 0; kt < 8; ++kt) {     // K = 256 = 8*32
        bf16x8 a[4], b[4];
        #pragma unroll
        for (int mt = 0; mt < 4; ++mt) {
            int ar = r0 + mt * 16 + l15;
            if (ar >= n_nodes) ar = n_nodes - 1;       // clamp (writes are guarded)
            // 8 contiguous fp32 along k: two float4
            const float4* p = &A4[ar * 64 + kt * 8 + lg * 2];
            float4 f0 = p[0], f1 = p[1];
            bf16x8 af;
            af[0] = (__bf16)f0.x; af[1] = (__bf16)f0.y;
            af[2] = (__bf16)f0.z; af[3] = (__bf16)f0.w;
            af[4] = (__bf16)f1.x; af[5] = (__bf16)f1.y;
            af[6] = (__bf16)f1.z; af[7] = (__bf16)f1.w;
            a[mt] = af;
        }
        #pragma unroll
        for (int nt = 0; nt < 4; ++nt)
            b[nt] = B8[(c0 + nt * 16 + l15) * 32 + kt * 4 + lg];
        #pragma unroll
        for (int mt = 0; mt < 4; ++mt)
            #pragma unroll
            for (int nt = 0; nt < 4; ++nt)
                acc[mt][nt] = __builtin_amdgcn_mfma_f32_16x16x32_bf16(
                                  a[mt], b[nt], acc[mt][nt], 0, 0, 0);
    }

    // C layout (verified): reg j -> row=(lane>>4)*4+j, col=lane&15
    #pragma unroll
    for (int mt = 0; mt < 4; ++mt) {
        #pragma unroll
        for (int j = 0; j < 4; ++j) {
            int row = r0 + mt * 16 + lg * 4 + j;
            if (row < n_nodes) {
                #pragma unroll
                for (int nt = 0; nt < 4; ++nt)
                    Y[row * 256 + c0 + nt * 16 + l15] = f2bf(acc[mt][nt][j]);
            }
        }
    }
}

// =====================================================================================
// K2: out = normalize(relu(mean(Y[nbrs], axis=1)))   -- fp32 out
// block = 256 thr = 8 groups x 32 lanes; group owns one node; lane owns 8 dims (16B).
// 16 outstanding dwordx4 loads per thread (256B in flight/lane).
// =====================================================================================
__global__ __launch_bounds__(256) void k_gather_norm(
        const int* __restrict__ nbrs,
        const uint4* __restrict__ Yq,    // [n][32] (8 bf16 per uint4)
        float* __restrict__ out, int n_nodes) {
    __shared__ int snbr[128];
    int t = threadIdx.x;
    int nb0 = blockIdx.x * 8;
    if (t < 128) {
        int i = nb0 * 16 + t;
        snbr[t] = (i < n_nodes * 16) ? nbrs[i] : 0;
    }
    __syncthreads();

    int g    = t >> 5;          // group 0..7 -> node
    int d8   = t & 31;          // owns dims d8*8 .. d8*8+7
    int node = nb0 + g;

    float s[8];
    #pragma unroll
    for (int i = 0; i < 8; ++i) s[i] = 0.f;

    if (node < n_nodes) {
        #pragma unroll
        for (int j = 0; j < 16; ++j) {
            uint4 u = Yq[(size_t)snbr[g * 16 + j] * 32 + d8];
            s[0] += bflo(u.x); s[1] += bfhi(u.x);
            s[2] += bflo(u.y); s[3] += bfhi(u.y);
            s[4] += bflo(u.z); s[5] += bfhi(u.z);
            s[6] += bflo(u.w); s[7] += bfhi(u.w);
        }
    }

    // mean + relu + partial ssq
    float q = 0.f;
    #pragma unroll
    for (int i = 0; i < 8; ++i) {
        float v = fmaxf(s[i] * 0.0625f, 0.f);
        s[i] = v;
        q += v * v;
    }
    // reduce across the 32 lanes of this group (xor of bits 0..4 stays in-group)
    #pragma unroll
    for (int m = 1; m < 32; m <<= 1)
        q += __shfl_xor(q, m, 64);
    float iv = 1.f / fmaxf(sqrtf(q), 1e-12f);

    if (node < n_nodes) {
        float4* o4 = reinterpret_cast<float4*>(out) + node * 64 + d8 * 2;
        o4[0] = (float4){s[0] * iv, s[1] * iv, s[2] * iv, s[3] * iv};
        o4[1] = (float4){s[4] * iv, s[5] * iv, s[6] * iv, s[7] * iv};
    }
}

// =====================================================================================
// Fallback (only if ws too small): fully fused fp32, one block per node
// =====================================================================================
__global__ __launch_bounds__(256) void k_fused_fallback(const int* __restrict__ nbrs,
        const float* __restrict__ emb, const float* __restrict__ W,
        float* __restrict__ out, int n_nodes) {
    __shared__ __align__(16) float h[256];
    __shared__ int sn[16];
    __shared__ float sred[4];
    int i = blockIdx.x;
    int t = threadIdx.x;
    if (t < 16) sn[t] = nbrs[i * 16 + t];
    __syncthreads();
    float s = 0.f;
    #pragma unroll
    for (int j = 0; j < 16; ++j) s += emb[sn[j] * 256 + t];
    h[t] = s * 0.0625f;
    __syncthreads();
    const float4* W4 = reinterpret_cast<const float4*>(W);
    const float4* h4 = reinterpret_cast<const float4*>(h);
    float y = 0.f;
    #pragma unroll 8
    for (int k4 = 0; k4 < 64; ++k4) {
        float4 wv = W4[t * 64 + k4];
        float4 hv = h4[k4];
        y += wv.x * hv.x + wv.y * hv.y + wv.z * hv.z + wv.w * hv.w;
    }
    y = fmaxf(y, 0.f);
    float q = y * y;
    #pragma unroll
    for (int m = 1; m < 64; m <<= 1) q += __shfl_xor(q, m, 64);
    if ((t & 63) == 0) sred[t >> 6] = q;
    __syncthreads();
    float tot = sred[0] + sred[1] + sred[2] + sred[3];
    out[i * 256 + t] = y * (1.f / fmaxf(sqrtf(tot), 1e-12f));
}

extern "C" void kernel_launch(void* const* d_in, const int* in_sizes, int n_in,
                              void* d_out, int out_size, void* d_ws, size_t ws_size,
                              hipStream_t stream) {
    const int*   nbrs = (const int*)d_in[0];     // [n_nodes, 16]
    const float* emb  = (const float*)d_in[1];   // [n_nodes, 256] fp32
    const float* W    = (const float*)d_in[2];   // [256, 256] fp32 (out, in)
    float* out = (float*)d_out;

    const int degree = 16, dim = 256;
    const int n_nodes = in_sizes[0] / degree;            // 50000

    // ws layout: bf16 W (128 KiB) + bf16 Y (n*512 B)
    size_t off_w = 0;
    size_t sz_w  = (size_t)dim * dim * 2;
    size_t off_y = (off_w + sz_w + 255) & ~(size_t)255;
    size_t sz_y  = (size_t)n_nodes * dim * 2;
    size_t need  = off_y + sz_y;

    if (ws_size < need) {
        k_fused_fallback<<<n_nodes, 256, 0, stream>>>(nbrs, emb, W, out, n_nodes);
        return;
    }

    char* ws = (char*)d_ws;
    u16* w_bf = (u16*)(ws + off_w);
    u16* y_bf = (u16*)(ws + off_y);

    int n4w = dim * dim / 4;                              // 16384
    k_convert<<<(n4w + 255) / 256, 256, 0, stream>>>(W, w_bf, n4w);

    int gblk = (n_nodes + 63) / 64;                       // 782
    k_emb_gemm<<<gblk, 256, 0, stream>>>(emb, w_bf, y_bf, n_nodes);

    int nblk = (n_nodes + 7) / 8;                         // 6250
    k_gather_norm<<<nblk, 256, 0, stream>>>(nbrs, (const uint4*)y_bf, out, n_nodes);
}

// Round 6
// 95.407 us; speedup vs baseline: 1.2257x; 1.2257x over previous
//
#include <hip/hip_runtime.h>
#include <hip/hip_bf16.h>

typedef unsigned short u16;
typedef __bf16 bf16x8 __attribute__((ext_vector_type(8)));
typedef float f32x4 __attribute__((ext_vector_type(4)));

// ---- manual fp32 -> bf16 (round-to-nearest-even) ----
__device__ __forceinline__ u16 f2bf(float f) {
    unsigned u = __float_as_uint(f);
    u = u + 0x7fffu + ((u >> 16) & 1u);   // RNE
    return (u16)(u >> 16);
}
__device__ __forceinline__ float bflo(unsigned u) { return __uint_as_float(u << 16); }
__device__ __forceinline__ float bfhi(unsigned u) { return __uint_as_float(u & 0xffff0000u); }

// =====================================================================================
// K0: fp32 -> bf16 convert (W only, 64Ki elements — tiny)
// =====================================================================================
__global__ __launch_bounds__(256) void k_convert(const float* __restrict__ src,
                                                 u16* __restrict__ dst, int n4) {
    int i = blockIdx.x * blockDim.x + threadIdx.x;
    if (i >= n4) return;
    float4 v = reinterpret_cast<const float4*>(src)[i];
    ushort4 o;
    o.x = f2bf(v.x); o.y = f2bf(v.y); o.z = f2bf(v.z); o.w = f2bf(v.w);
    reinterpret_cast<ushort4*>(dst)[i] = o;
}

// =====================================================================================
// K1: Y = emb @ W^T   (bf16 MFMA, coalesced LDS-staged A)
// block = 256 thr (4 waves); tile 64 rows x 256 cols; wave tile 64x64.
// A staged: 16 iters x (256 thr x float4) fully-coalesced reads, fp32->bf16 in-reg,
// LDS rows padded to 264 bf16 (528B) to break power-of-2 bank stride.
// =====================================================================================
__global__ __launch_bounds__(256) void k_emb_gemm(
        const float* __restrict__ emb,   // [n][256] fp32
        const u16* __restrict__ wbf,     // [256][256] bf16 (row = out_dim, col = k)
        u16* __restrict__ Y,             // [n][256] bf16
        int n_nodes) {
    __shared__ u16 As[64][264];          // 33,792 B
    int tid  = threadIdx.x;
    int lane = tid & 63;
    int w    = tid >> 6;
    int r0   = blockIdx.x * 64;
    int c0   = w * 64;
    int l15  = lane & 15;
    int lg   = lane >> 4;                // k-subblock of 8

    // ---- stage A (64 x 256 fp32 -> bf16 LDS), perfectly coalesced ----
    {
        const float4* E4 = reinterpret_cast<const float4*>(emb);
        int c16 = tid & 63;              // float4 column 0..63
        int rsub = tid >> 6;             // 0..3
        #pragma unroll
        for (int i = 0; i < 16; ++i) {
            int row = i * 4 + rsub;
            int gr  = r0 + row;
            if (gr >= n_nodes) gr = n_nodes - 1;       // clamp; writes guarded later
            float4 v = E4[(size_t)gr * 64 + c16];
            ushort4 o;
            o.x = f2bf(v.x); o.y = f2bf(v.y); o.z = f2bf(v.z); o.w = f2bf(v.w);
            *reinterpret_cast<ushort4*>(&As[row][c16 * 4]) = o;
        }
    }
    __syncthreads();

    const bf16x8* B8 = reinterpret_cast<const bf16x8*>(wbf);

    f32x4 acc[4][4];
    #pragma unroll
    for (int mt = 0; mt < 4; ++mt)
        #pragma unroll
        for (int nt = 0; nt < 4; ++nt)
            acc[mt][nt] = (f32x4){0.f, 0.f, 0.f, 0.f};

    #pragma unroll
    for (int kt = 0; kt < 8; ++kt) {     // K = 256 = 8*32
        bf16x8 a[4], b[4];
        #pragma unroll
        for (int mt = 0; mt < 4; ++mt)
            a[mt] = *reinterpret_cast<const bf16x8*>(&As[mt * 16 + l15][kt * 32 + lg * 8]);
        #pragma unroll
        for (int nt = 0; nt < 4; ++nt)
            b[nt] = B8[(c0 + nt * 16 + l15) * 32 + kt * 4 + lg];
        #pragma unroll
        for (int mt = 0; mt < 4; ++mt)
            #pragma unroll
            for (int nt = 0; nt < 4; ++nt)
                acc[mt][nt] = __builtin_amdgcn_mfma_f32_16x16x32_bf16(
                                  a[mt], b[nt], acc[mt][nt], 0, 0, 0);
    }

    // C layout (verified): reg j -> row=(lane>>4)*4+j, col=lane&15
    #pragma unroll
    for (int mt = 0; mt < 4; ++mt) {
        #pragma unroll
        for (int j = 0; j < 4; ++j) {
            int row = r0 + mt * 16 + lg * 4 + j;
            if (row < n_nodes) {
                #pragma unroll
                for (int nt = 0; nt < 4; ++nt)
                    Y[(size_t)row * 256 + c0 + nt * 16 + l15] = f2bf(acc[mt][nt][j]);
            }
        }
    }
}

// =====================================================================================
// K2: out = normalize(relu(mean(Y[nbrs], axis=1)))   -- fp32 out (nontemporal)
// block = 256 thr = 8 groups x 32 lanes; group owns one node; lane owns 8 dims (16B).
// 16 outstanding dwordx4 loads per thread.
// =====================================================================================
__global__ __launch_bounds__(256) void k_gather_norm(
        const int* __restrict__ nbrs,
        const uint4* __restrict__ Yq,    // [n][32] (8 bf16 per uint4)
        float* __restrict__ out, int n_nodes) {
    __shared__ int snbr[128];
    int t = threadIdx.x;
    int nb0 = blockIdx.x * 8;
    if (t < 128) {
        int i = nb0 * 16 + t;
        snbr[t] = (i < n_nodes * 16) ? nbrs[i] : 0;
    }
    __syncthreads();

    int g    = t >> 5;          // group 0..7 -> node
    int d8   = t & 31;          // owns dims d8*8 .. d8*8+7
    int node = nb0 + g;

    float s[8];
    #pragma unroll
    for (int i = 0; i < 8; ++i) s[i] = 0.f;

    if (node < n_nodes) {
        #pragma unroll
        for (int j = 0; j < 16; ++j) {
            uint4 u = Yq[(size_t)snbr[g * 16 + j] * 32 + d8];
            s[0] += bflo(u.x); s[1] += bfhi(u.x);
            s[2] += bflo(u.y); s[3] += bfhi(u.y);
            s[4] += bflo(u.z); s[5] += bfhi(u.z);
            s[6] += bflo(u.w); s[7] += bfhi(u.w);
        }
    }

    // mean + relu + partial ssq
    float q = 0.f;
    #pragma unroll
    for (int i = 0; i < 8; ++i) {
        float v = fmaxf(s[i] * 0.0625f, 0.f);
        s[i] = v;
        q += v * v;
    }
    // reduce across the 32 lanes of this group (xor of bits 0..4 stays in-group)
    #pragma unroll
    for (int m = 1; m < 32; m <<= 1)
        q += __shfl_xor(q, m, 64);
    float iv = 1.f / fmaxf(sqrtf(q), 1e-12f);

    if (node < n_nodes) {
        // native clang vector type for the nontemporal builtin
        f32x4* o4 = reinterpret_cast<f32x4*>(out + (size_t)node * 256 + d8 * 8);
        f32x4 v0 = {s[0] * iv, s[1] * iv, s[2] * iv, s[3] * iv};
        f32x4 v1 = {s[4] * iv, s[5] * iv, s[6] * iv, s[7] * iv};
        __builtin_nontemporal_store(v0, &o4[0]);
        __builtin_nontemporal_store(v1, &o4[1]);
    }
}

// =====================================================================================
// Fallback (only if ws too small): fully fused fp32, one block per node
// =====================================================================================
__global__ __launch_bounds__(256) void k_fused_fallback(const int* __restrict__ nbrs,
        const float* __restrict__ emb, const float* __restrict__ W,
        float* __restrict__ out, int n_nodes) {
    __shared__ __align__(16) float h[256];
    __shared__ int sn[16];
    __shared__ float sred[4];
    int i = blockIdx.x;
    int t = threadIdx.x;
    if (t < 16) sn[t] = nbrs[i * 16 + t];
    __syncthreads();
    float s = 0.f;
    #pragma unroll
    for (int j = 0; j < 16; ++j) s += emb[sn[j] * 256 + t];
    h[t] = s * 0.0625f;
    __syncthreads();
    const float4* W4 = reinterpret_cast<const float4*>(W);
    const float4* h4 = reinterpret_cast<const float4*>(h);
    float y = 0.f;
    #pragma unroll 8
    for (int k4 = 0; k4 < 64; ++k4) {
        float4 wv = W4[t * 64 + k4];
        float4 hv = h4[k4];
        y += wv.x * hv.x + wv.y * hv.y + wv.z * hv.z + wv.w * hv.w;
    }
    y = fmaxf(y, 0.f);
    float q = y * y;
    #pragma unroll
    for (int m = 1; m < 64; m <<= 1) q += __shfl_xor(q, m, 64);
    if ((t & 63) == 0) sred[t >> 6] = q;
    __syncthreads();
    float tot = sred[0] + sred[1] + sred[2] + sred[3];
    out[i * 256 + t] = y * (1.f / fmaxf(sqrtf(tot), 1e-12f));
}

extern "C" void kernel_launch(void* const* d_in, const int* in_sizes, int n_in,
                              void* d_out, int out_size, void* d_ws, size_t ws_size,
                              hipStream_t stream) {
    const int*   nbrs = (const int*)d_in[0];     // [n_nodes, 16]
    const float* emb  = (const float*)d_in[1];   // [n_nodes, 256] fp32
    const float* W    = (const float*)d_in[2];   // [256, 256] fp32 (out, in)
    float* out = (float*)d_out;

    const int degree = 16, dim = 256;
    const int n_nodes = in_sizes[0] / degree;            // 50000

    // ws layout: bf16 W (128 KiB) + bf16 Y (n*512 B)
    size_t off_w = 0;
    size_t sz_w  = (size_t)dim * dim * 2;
    size_t off_y = (off_w + sz_w + 255) & ~(size_t)255;
    size_t sz_y  = (size_t)n_nodes * dim * 2;
    size_t need  = off_y + sz_y;

    if (ws_size < need) {
        k_fused_fallback<<<n_nodes, 256, 0, stream>>>(nbrs, emb, W, out, n_nodes);
        return;
    }

    char* ws = (char*)d_ws;
    u16* w_bf = (u16*)(ws + off_w);
    u16* y_bf = (u16*)(ws + off_y);

    int n4w = dim * dim / 4;                              // 16384
    k_convert<<<(n4w + 255) / 256, 256, 0, stream>>>(W, w_bf, n4w);

    int gblk = (n_nodes + 63) / 64;                       // 782
    k_emb_gemm<<<gblk, 256, 0, stream>>>(emb, w_bf, y_bf, n_nodes);

    int nblk = (n_nodes + 7) / 8;                         // 6250
    k_gather_norm<<<nblk, 256, 0, stream>>>(nbrs, (const uint4*)y_bf, out, n_nodes);
}